// Round 4
// baseline (378.439 us; speedup 1.0000x reference)
//
#include <hip/hip_runtime.h>
#include <hip/hip_fp16.h>

// Fused 8-step diffusion, v5: streaming weight fetch + zero-halo planes.
//
// v4 post-mortem (clean, no spill): dur tracks bytes fetched (v1 92MB/110us,
// v4 113MB/127us) while VALU=20%, HBM=13%, conflicts=0 -> fetch-throughput-
// bound at a DEGRADED effective rate (~1 TB/s). The weight pattern (512B
// chunks scattered k-inner across nine 64KB-strided tap planes) defeats DRAM
// streaming; v2's linear scratch spill streams hit 2.3 TB/s in the same
// kernel, so the memory system is capable of more.
//
// v5 changes:
//  - ONE block per plane: 256 blocks x 1024 threads (16 waves). Thread =
//    4 rows x 4 cols (rg=tid>>5 in 0..31, quad=tid&31). NO halo: fetch is
//    compulsory-only (151MB wgt + 17MB x), no redundant compute, and plane
//    edges are true zeros (pad-row pass deleted).
//  - k-OUTER / p-inner weight loads: per tap, each wave issues 4 dwordx4
//    back-to-back covering a contiguous 4KB; 16 waves sweep the full 64KB
//    tap plane; block's total DRAM footprint = one sequential 589KB run.
//    Taps packed fp16 UNNORMALIZED with fp32 sums inline; one post-pass
//    unpack-scale-repack applies 1/sum|w| (~400 VALU, trivial).
//  - Step loop: v1-proven two-barrier boundary exchange (v3's single-barrier
//    raced), NRG=32, LDS 32KB. fp32 accumulate (fp16 acc would drift over
//    8 steps vs the 0.014 threshold).

constexpr int H = 128, W = 128, PLANE = H * W;
constexpr int NSTEP = 8;
constexpr int RPT  = 4;            // rows per thread (128 rows / 32 rg)
constexpr int NRG  = 32;

// 6-wide column window (cols j0-1 .. j0+4) from a float4 row segment
#define MKWIN(D, V) do {                                                     \
    (D)[1] = (V).x; (D)[2] = (V).y; (D)[3] = (V).z; (D)[4] = (V).w;          \
    float _l = __shfl_up((V).w, 1);                                          \
    float _r = __shfl_down((V).x, 1);                                        \
    (D)[0] = (quad == 0)  ? 0.f : _l;                                        \
    (D)[5] = (quad == 31) ? 0.f : _r;                                        \
} while (0)

__global__ __launch_bounds__(1024)
void diff_fused(const float* __restrict__ xin,
                const float* __restrict__ wgt,
                float* __restrict__ out)
{
    __shared__ float ldsT[NRG][W];      // each rg's top row    (16 KB)
    __shared__ float ldsB[NRG][W];      // each rg's bottom row (16 KB)

    const int tid   = threadIdx.x;
    const int quad  = tid & 31;         // cols 4q..4q+3
    const int rg    = tid >> 5;         // 0..31
    const int j0    = quad * 4;
    const int r0    = rg * RPT;         // this thread's first row (0..124)
    const size_t pbase = (size_t)blockIdx.x * PLANE;

    const float* __restrict__ xp = xin + pbase;
    const float* __restrict__ wb = wgt + pbase * 9;

    // ---- weights: k-outer streaming load, pack |.| fp16 unnormalized,
    //      accumulate fp32 tap-sums; normalize in a post-pass ----
    __half2 wh[RPT][9][2];              // 72 VGPRs (packed |w|, then normalized)
    float s[RPT][4];
    #pragma unroll
    for (int p = 0; p < RPT; ++p) { s[p][0] = s[p][1] = s[p][2] = s[p][3] = 0.f; }

    #pragma unroll
    for (int k = 0; k < 9; ++k) {
        const float* wk = wb + (size_t)k * PLANE + r0 * W + j0;
        float4 v[RPT];
        #pragma unroll
        for (int p = 0; p < RPT; ++p)     // 4 back-to-back dwordx4: 4KB/wave
            v[p] = *reinterpret_cast<const float4*>(wk + p * W);
        #pragma unroll
        for (int p = 0; p < RPT; ++p) {
            const float a0 = fabsf(v[p].x), a1 = fabsf(v[p].y);
            const float a2 = fabsf(v[p].z), a3 = fabsf(v[p].w);
            s[p][0] += a0; s[p][1] += a1; s[p][2] += a2; s[p][3] += a3;
            wh[p][k][0] = __halves2half2(__float2half_rn(a0), __float2half_rn(a1));
            wh[p][k][1] = __halves2half2(__float2half_rn(a2), __float2half_rn(a3));
        }
    }
    // normalization post-pass: unpack, scale by 1/sum, repack
    #pragma unroll
    for (int p = 0; p < RPT; ++p) {
        const float i0 = 1.f / s[p][0], i1 = 1.f / s[p][1];
        const float i2 = 1.f / s[p][2], i3 = 1.f / s[p][3];
        #pragma unroll
        for (int k = 0; k < 9; ++k) {
            wh[p][k][0] = __halves2half2(
                __float2half_rn(__low2float (wh[p][k][0]) * i0),
                __float2half_rn(__high2float(wh[p][k][0]) * i1));
            wh[p][k][1] = __halves2half2(
                __float2half_rn(__low2float (wh[p][k][1]) * i2),
                __float2half_rn(__high2float(wh[p][k][1]) * i3));
        }
    }

    // ---- x rows into registers ----
    float4 xr[RPT];
    #pragma unroll
    for (int p = 0; p < RPT; ++p)
        xr[p] = *reinterpret_cast<const float4*>(xp + (r0 + p) * W + j0);

    // ---- 8 fused steps, zero global traffic, two barriers/step ----
    #pragma unroll 1
    for (int st = 0; st < NSTEP; ++st) {
        *reinterpret_cast<float4*>(&ldsT[rg][j0]) = xr[0];
        *reinterpret_cast<float4*>(&ldsB[rg][j0]) = xr[RPT - 1];
        __syncthreads();
        float4 up = make_float4(0.f, 0.f, 0.f, 0.f);   // row r0-1 (true 0 at rg=0)
        float4 dn = make_float4(0.f, 0.f, 0.f, 0.f);   // row r0+4 (true 0 at rg=31)
        if (rg > 0)       up = *reinterpret_cast<const float4*>(&ldsB[rg - 1][j0]);
        if (rg < NRG - 1) dn = *reinterpret_cast<const float4*>(&ldsT[rg + 1][j0]);
        __syncthreads();   // reads done before next step's writes

        float win[3][6];
        MKWIN(win[0], up);       // input row r0-1
        MKWIN(win[1], xr[0]);    // input row r0
        #pragma unroll
        for (int p = 0; p < RPT; ++p) {
            if (p < RPT - 1) { MKWIN(win[(p + 2) % 3], xr[p + 1]); }
            else             { MKWIN(win[(p + 2) % 3], dn); }
            float a0 = 0.f, a1 = 0.f, a2 = 0.f, a3 = 0.f;
            #pragma unroll
            for (int di = 0; di < 3; ++di) {
                #pragma unroll
                for (int dj = 0; dj < 3; ++dj) {
                    const int k = di * 3 + dj;
                    const __half2 w0 = wh[p][k][0];
                    const __half2 w1 = wh[p][k][1];
                    a0 = fmaf(__low2float (w0), win[(p + di) % 3][dj + 0], a0);
                    a1 = fmaf(__high2float(w0), win[(p + di) % 3][dj + 1], a1);
                    a2 = fmaf(__low2float (w1), win[(p + di) % 3][dj + 2], a2);
                    a3 = fmaf(__high2float(w1), win[(p + di) % 3][dj + 3], a3);
                }
            }
            xr[p] = make_float4(a0, a1, a2, a3);
        }
    }

    // ---- store all owned rows (coalesced float4, full plane) ----
    float* __restrict__ op = out + pbase;
    #pragma unroll
    for (int p = 0; p < RPT; ++p)
        *reinterpret_cast<float4*>(op + (r0 + p) * W + j0) = xr[p];
}

extern "C" void kernel_launch(void* const* d_in, const int* in_sizes, int n_in,
                              void* d_out, int out_size, void* d_ws, size_t ws_size,
                              hipStream_t stream)
{
    const float* x = (const float*)d_in[0];
    const float* w = (const float*)d_in[1];
    float* out = (float*)d_out;
    (void)d_ws; (void)ws_size; (void)in_sizes; (void)n_in; (void)out_size;

    // 256 blocks = 1 per (n,c) plane, 1024 threads (16 waves)
    diff_fused<<<dim3(4 * 64), dim3(1024), 0, stream>>>(x, w, out);
}